// Round 1
// baseline (10818.658 us; speedup 1.0000x reference)
//
#include <hip/hip_runtime.h>
#include <cstdint>
#include <cstddef>

// ---- problem dims ----
#define BB    8
#define CCH   2
#define IMGD  256
#define PDIM  16
#define DD    1024
#define LLAY  8
#define NHEAD 16
#define DFFD  4096
#define HPD   16
#define NTOK  256          // patch tokens
#define SD    257          // + cls
#define HDD   64
#define MTOK  (BB*SD)      // 2056
#define MPAT  (BB*NTOK)    // 2048

// =====================================================================
// Generic fp32 tiled GEMM: C[m,n] = act(A[m,k]*B[k,n] + bias[n]) + Cin[m,n]
// BM=BN=64, BK=16, 256 threads, 4x4 per thread.
// Requires: K%16==0, N%64==0 (true for all call sites: K in {512,1024,4096},
// N in {512,1024,4096}). M guarded (2056 = 32*64+8).
// ACT: 0=none, 1=exact GELU (erf).
// =====================================================================
template<int ACT>
__global__ __launch_bounds__(256) void gemm_f32(
    const float* __restrict__ A, const float* __restrict__ Bm,
    const float* __restrict__ bias, const float* __restrict__ Cin,
    float* __restrict__ Cout, int M, int Nn, int Kk)
{
    __shared__ float As[16][68];   // [k][m], stride 68 floats = 272B (16B aligned)
    __shared__ float Bs[16][64];   // [k][n]
    const int tid = threadIdx.x;
    const int m0 = blockIdx.y * 64, n0 = blockIdx.x * 64;
    const int tx = tid & 15, ty = tid >> 4;

    const int la_m = tid >> 2;          // 0..63
    const int la_k = (tid & 3) << 2;    // 0,4,8,12
    const int lb_k = tid >> 4;          // 0..15
    const int lb_n = (tid & 15) << 2;   // 0..60

    float acc[4][4] = {};

    for (int k0 = 0; k0 < Kk; k0 += 16) {
        // stage A (with M guard) transposed into LDS
        float4 av = make_float4(0.f, 0.f, 0.f, 0.f);
        const int am = m0 + la_m;
        if (am < M) av = *(const float4*)(A + (size_t)am * Kk + k0 + la_k);
        As[la_k + 0][la_m] = av.x;
        As[la_k + 1][la_m] = av.y;
        As[la_k + 2][la_m] = av.z;
        As[la_k + 3][la_m] = av.w;
        // stage B
        const float4 bv = *(const float4*)(Bm + (size_t)(k0 + lb_k) * Nn + n0 + lb_n);
        *(float4*)&Bs[lb_k][lb_n] = bv;
        __syncthreads();
        #pragma unroll
        for (int kk = 0; kk < 16; ++kk) {
            const float4 a4 = *(const float4*)&As[kk][ty << 2];
            const float4 b4 = *(const float4*)&Bs[kk][tx << 2];
            acc[0][0] = fmaf(a4.x, b4.x, acc[0][0]);
            acc[0][1] = fmaf(a4.x, b4.y, acc[0][1]);
            acc[0][2] = fmaf(a4.x, b4.z, acc[0][2]);
            acc[0][3] = fmaf(a4.x, b4.w, acc[0][3]);
            acc[1][0] = fmaf(a4.y, b4.x, acc[1][0]);
            acc[1][1] = fmaf(a4.y, b4.y, acc[1][1]);
            acc[1][2] = fmaf(a4.y, b4.z, acc[1][2]);
            acc[1][3] = fmaf(a4.y, b4.w, acc[1][3]);
            acc[2][0] = fmaf(a4.z, b4.x, acc[2][0]);
            acc[2][1] = fmaf(a4.z, b4.y, acc[2][1]);
            acc[2][2] = fmaf(a4.z, b4.z, acc[2][2]);
            acc[2][3] = fmaf(a4.z, b4.w, acc[2][3]);
            acc[3][0] = fmaf(a4.w, b4.x, acc[3][0]);
            acc[3][1] = fmaf(a4.w, b4.y, acc[3][1]);
            acc[3][2] = fmaf(a4.w, b4.z, acc[3][2]);
            acc[3][3] = fmaf(a4.w, b4.w, acc[3][3]);
        }
        __syncthreads();
    }

    #pragma unroll
    for (int i = 0; i < 4; ++i) {
        const int m = m0 + (ty << 2) + i;
        if (m >= M) continue;
        #pragma unroll
        for (int j = 0; j < 4; ++j) {
            const int n = n0 + (tx << 2) + j;
            float v = acc[i][j];
            if (bias) v += bias[n];
            if (ACT == 1) v = 0.5f * v * (1.f + erff(v * 0.70710678118654752f));
            if (Cin)  v += Cin[(size_t)m * Nn + n];
            Cout[(size_t)m * Nn + n] = v;
        }
    }
}

// =====================================================================
// im2col for patch embed: A[m= b*256 + hp*16 + wp][k = c*256 + p*16 + q]
// =====================================================================
__global__ __launch_bounds__(256) void im2col_k(const float* __restrict__ imgs,
                                                float* __restrict__ Ao)
{
    const int idx = blockIdx.x * 256 + threadIdx.x;   // 2048*512 total
    const int k = idx & 511, m = idx >> 9;
    const int b = m >> 8, n = m & 255;
    const int hp = n >> 4, wp = n & 15;
    const int c = k >> 8, p = (k >> 4) & 15, q = k & 15;
    Ao[idx] = imgs[(((size_t)b * CCH + c) * IMGD + hp * PDIM + p) * IMGD + wp * PDIM + q];
}

// X[b,0,:] = cls ; X[b,1+n,:] = RES[b,n,:]
__global__ __launch_bounds__(256) void build_x_k(const float* __restrict__ RES,
                                                 const float* __restrict__ cls,
                                                 float* __restrict__ X)
{
    const int idx = blockIdx.x * 256 + threadIdx.x;   // MTOK*DD = 2,105,344
    const int d = idx & 1023;
    const int r = idx >> 10;                          // b*257 + s
    const int b = r / SD;
    const int s = r - b * SD;
    X[idx] = (s == 0) ? cls[d] : RES[((size_t)(b * NTOK + s - 1)) * DD + d];
}

// =====================================================================
// LayerNorm over D=1024, one block (4 waves) per row.
// =====================================================================
__global__ __launch_bounds__(256) void ln_rows(const float* __restrict__ X,
                                               const float* __restrict__ w,
                                               const float* __restrict__ bsrc,
                                               float* __restrict__ Y)
{
    const int row = blockIdx.x;
    const int tid = threadIdx.x;
    const float* xr = X + (size_t)row * DD;
    const float4 v = *(const float4*)(xr + tid * 4);
    float s  = v.x + v.y + v.z + v.w;
    float s2 = v.x * v.x + v.y * v.y + v.z * v.z + v.w * v.w;
    #pragma unroll
    for (int off = 1; off < 64; off <<= 1) {
        s  += __shfl_xor(s, off);
        s2 += __shfl_xor(s2, off);
    }
    __shared__ float rs[4], rs2[4];
    if ((tid & 63) == 0) { rs[tid >> 6] = s; rs2[tid >> 6] = s2; }
    __syncthreads();
    s  = rs[0] + rs[1] + rs[2] + rs[3];
    s2 = rs2[0] + rs2[1] + rs2[2] + rs2[3];
    const float mu  = s * (1.f / 1024.f);
    const float var = fmaf(-mu, mu, s2 * (1.f / 1024.f));
    const float ri  = rsqrtf(var + 1e-5f);
    const float4 wv = *(const float4*)(w + tid * 4);
    const float4 bv = *(const float4*)(bsrc + tid * 4);
    float4 o;
    o.x = (v.x - mu) * ri * wv.x + bv.x;
    o.y = (v.y - mu) * ri * wv.y + bv.y;
    o.z = (v.z - mu) * ri * wv.z + bv.z;
    o.w = (v.w - mu) * ri * wv.w + bv.w;
    *(float4*)(Y + (size_t)row * DD + tid * 4) = o;
}

// =====================================================================
// Attention scores: logits[b,h,q,k] = scale * <Q[b,q,h,:], K[b,k,h,:]>
//                                     + decay(h) * manhattan(q,k)
// grid (9 qtiles, 9 ktiles, B*NH), 32x32 tile per block.
// =====================================================================
__global__ __launch_bounds__(256) void attn_scores(const float* __restrict__ Q,
                                                   const float* __restrict__ Km,
                                                   float* __restrict__ Lg)
{
    const int bh = blockIdx.z;
    const int b = bh >> 4, h = bh & 15;
    const int q0 = blockIdx.x * 32, k0 = blockIdx.y * 32;
    __shared__ float Qs[32][65];
    __shared__ float KsT[64][33];
    const int tid = threadIdx.x;
    for (int li = tid; li < 2048; li += 256) {
        const int r = li >> 6, d = li & 63;
        const int sq = q0 + r, sk = k0 + r;
        Qs[r][d]  = (sq < SD) ? Q[((size_t)(b * SD + sq)) * DD + h * HDD + d] : 0.f;
        KsT[d][r] = (sk < SD) ? Km[((size_t)(b * SD + sk)) * DD + h * HDD + d] : 0.f;
    }
    __syncthreads();
    const int tx = tid & 31, ty = tid >> 5;  // ty 0..7
    float acc[4] = {0.f, 0.f, 0.f, 0.f};
    for (int d = 0; d < 64; ++d) {
        const float kv = KsT[d][tx];
        #pragma unroll
        for (int i = 0; i < 4; ++i) acc[i] = fmaf(Qs[ty + 8 * i][d], kv, acc[i]);
    }
    const float dec = logf(1.f - exp2f(-1.f - (float)h));   // negative
    const int sk = k0 + tx;
    const float scale = 0.125f;   // 64^-0.5
    #pragma unroll
    for (int i = 0; i < 4; ++i) {
        const int sq = q0 + ty + 8 * i;
        if (sq < SD && sk < SD) {
            float mv = 0.f;
            if (sq > 0 && sk > 0) {
                const int nq = sq - 1, nk = sk - 1;
                const int dist = abs((nq >> 4) - (nk >> 4)) + abs((nq & 15) - (nk & 15));
                mv = dec * (float)dist;
            }
            Lg[((size_t)bh * SD + sq) * SD + sk] = acc[i] * scale + mv;
        }
    }
}

// row softmax over 257, one wave per row, 4 rows per block.
__global__ __launch_bounds__(256) void softmax_rows(float* __restrict__ Lg)
{
    const int row = blockIdx.x * 4 + (threadIdx.x >> 6);
    const int lane = threadIdx.x & 63;
    float* p = Lg + (size_t)row * SD;
    float v0 = p[lane];
    float v1 = p[lane + 64];
    float v2 = p[lane + 128];
    float v3 = p[lane + 192];
    float v4 = (lane == 0) ? p[256] : -3.4e38f;
    float mx = fmaxf(fmaxf(fmaxf(v0, v1), fmaxf(v2, v3)), v4);
    #pragma unroll
    for (int off = 1; off < 64; off <<= 1) mx = fmaxf(mx, __shfl_xor(mx, off));
    const float e0 = expf(v0 - mx);
    const float e1 = expf(v1 - mx);
    const float e2 = expf(v2 - mx);
    const float e3 = expf(v3 - mx);
    const float e4 = (lane == 0) ? expf(v4 - mx) : 0.f;
    float sum = e0 + e1 + e2 + e3 + e4;
    #pragma unroll
    for (int off = 1; off < 64; off <<= 1) sum += __shfl_xor(sum, off);
    const float inv = 1.f / sum;
    p[lane]       = e0 * inv;
    p[lane + 64]  = e1 * inv;
    p[lane + 128] = e2 * inv;
    p[lane + 192] = e3 * inv;
    if (lane == 0) p[256] = e4 * inv;
}

// O[b,q,h,d] = sum_k P[b,h,q,k] * V[b,k,h,d]; grid (9 qtiles, B*NH)
__global__ __launch_bounds__(256) void attn_av(const float* __restrict__ Pm,
                                               const float* __restrict__ V,
                                               float* __restrict__ O)
{
    const int bh = blockIdx.y;
    const int b = bh >> 4, h = bh & 15;
    const int q0 = blockIdx.x * 32;
    const int tid = threadIdx.x;
    const int d = tid & 63, qg = tid >> 6;   // 0..3
    __shared__ float Ps[32][33];
    __shared__ float Vs[32][64];
    float acc[8] = {};
    const float* Prow = Pm + (size_t)bh * SD * SD;
    for (int k0 = 0; k0 < SD; k0 += 32) {
        for (int li = tid; li < 1024; li += 256) {
            const int q = li >> 5, kk = li & 31;
            const int sq = q0 + q, sk = k0 + kk;
            Ps[q][kk] = (sq < SD && sk < SD) ? Prow[(size_t)sq * SD + sk] : 0.f;
        }
        for (int li = tid; li < 2048; li += 256) {
            const int kk = li >> 6, dd = li & 63;
            const int sk = k0 + kk;
            Vs[kk][dd] = (sk < SD) ? V[((size_t)(b * SD + sk)) * DD + h * HDD + dd] : 0.f;
        }
        __syncthreads();
        #pragma unroll
        for (int kk = 0; kk < 32; ++kk) {
            const float vv = Vs[kk][d];
            #pragma unroll
            for (int i = 0; i < 8; ++i) acc[i] = fmaf(Ps[qg * 8 + i][kk], vv, acc[i]);
        }
        __syncthreads();
    }
    #pragma unroll
    for (int i = 0; i < 8; ++i) {
        const int sq = q0 + qg * 8 + i;
        if (sq < SD) O[((size_t)(b * SD + sq)) * DD + h * HDD + d] = acc[i];
    }
}

// =====================================================================
// PGSA gate + residual: one block per (b, d-channel), 256 threads = tokens.
// RES[b,n,d] = t*sigmoid(y) + RES[b,n,d]
// =====================================================================
__global__ __launch_bounds__(256) void pgsa_k(const float* __restrict__ Xf,
                                              float* __restrict__ RES)
{
    const int bd = blockIdx.x;          // B*D = 8192
    const int b = bd >> 10, dch = bd & 1023;
    const int n = threadIdx.x;
    const float t = Xf[((size_t)(b * SD + 1 + n)) * DD + dch];
    __shared__ float red[4];
    float s = t;
    #pragma unroll
    for (int off = 1; off < 64; off <<= 1) s += __shfl_xor(s, off);
    if ((n & 63) == 0) red[n >> 6] = s;
    __syncthreads();
    const float mu = (red[0] + red[1] + red[2] + red[3]) * (1.f / 256.f);
    const float xm = t - mu;
    const float xm2 = xm * xm;
    __syncthreads();
    float s2 = xm2;
    #pragma unroll
    for (int off = 1; off < 64; off <<= 1) s2 += __shfl_xor(s2, off);
    if ((n & 63) == 0) red[n >> 6] = s2;
    __syncthreads();
    const float tot2 = red[0] + red[1] + red[2] + red[3];
    const float y = xm2 / (4.f * (tot2 * (1.f / 255.f) + 1e-4f)) + 0.5f;
    const float sig = 1.f / (1.f + expf(-y));
    const size_t ri = ((size_t)b * NTOK + n) * DD + dch;
    RES[ri] = fmaf(t, sig, RES[ri]);
}

// out[b, c, hp*16+p, wp*16+q] = PRED[b*256 + hp*16+wp][(p*16+q)*2 + c]
__global__ __launch_bounds__(256) void unpatch_k(const float* __restrict__ PRED,
                                                 float* __restrict__ out)
{
    const int idx = blockIdx.x * 256 + threadIdx.x;   // 1,048,576
    const int j = idx & 255, i = (idx >> 8) & 255;
    const int c = (idx >> 16) & 1, b = idx >> 17;
    const int hp = i >> 4, p = i & 15, wp = j >> 4, q = j & 15;
    out[idx] = PRED[((size_t)b * NTOK + hp * 16 + wp) * 512 + (p * 16 + q) * 2 + c];
}

// =====================================================================
static inline void gemm(hipStream_t st, const float* A, const float* Bm,
                        const float* bias, const float* Cin, float* Cout,
                        int M, int Nn, int Kk, int act)
{
    dim3 grid(Nn / 64, (M + 63) / 64);
    if (act) hipLaunchKernelGGL((gemm_f32<1>), grid, dim3(256), 0, st, A, Bm, bias, Cin, Cout, M, Nn, Kk);
    else     hipLaunchKernelGGL((gemm_f32<0>), grid, dim3(256), 0, st, A, Bm, bias, Cin, Cout, M, Nn, Kk);
}

extern "C" void kernel_launch(void* const* d_in, const int* in_sizes, int n_in,
                              void* d_out, int out_size, void* d_ws, size_t ws_size,
                              hipStream_t stream)
{
    const float* imgs     = (const float*)d_in[0];
    const float* patch_w  = (const float*)d_in[1];
    const float* patch_b  = (const float*)d_in[2];
    const float* cls_tok  = (const float*)d_in[3];
    const float* ln1_w    = (const float*)d_in[4];
    const float* ln1_b    = (const float*)d_in[5];
    const float* wq       = (const float*)d_in[6];
    const float* wk       = (const float*)d_in[7];
    const float* wv       = (const float*)d_in[8];
    const float* bq       = (const float*)d_in[9];
    const float* bk       = (const float*)d_in[10];
    const float* bv       = (const float*)d_in[11];
    const float* wo       = (const float*)d_in[12];
    const float* bo       = (const float*)d_in[13];
    const float* ln2_w    = (const float*)d_in[14];
    const float* ln2_b    = (const float*)d_in[15];
    const float* w1       = (const float*)d_in[16];
    const float* b1       = (const float*)d_in[17];
    const float* w2       = (const float*)d_in[18];
    const float* b2       = (const float*)d_in[19];
    const float* normf_w  = (const float*)d_in[20];
    const float* normf_b  = (const float*)d_in[21];
    const float* enpred_w = (const float*)d_in[22];
    const float* enpred_b = (const float*)d_in[23];
    float* out = (float*)d_out;

    // workspace layout (floats); total 21,078,144 floats = 84.3 MB
    float* ws  = (float*)d_ws;
    float* X   = ws;                         // [2056][1024]
    float* RES = X   + (size_t)MTOK * DD;    // [2048][1024]
    float* H   = RES + (size_t)MPAT * DD;    // [2056][1024]  (also attn O)
    float* Qb  = H   + (size_t)MTOK * DD;    // [2056][1024]  (also LN2 out)
    float* Kb  = Qb  + (size_t)MTOK * DD;
    float* Vb  = Kb  + (size_t)MTOK * DD;
    float* BIG = Vb  + (size_t)MTOK * DD;    // 8,454,272 fl: logits / MLP hidden / im2col / pred

    // ---- patch embed ----
    hipLaunchKernelGGL(im2col_k, dim3(4096), dim3(256), 0, stream, imgs, BIG);
    gemm(stream, BIG, patch_w, patch_b, nullptr, RES, MPAT, DD, CCH * PDIM * PDIM, 0);
    hipLaunchKernelGGL(build_x_k, dim3(8224), dim3(256), 0, stream, RES, cls_tok, X);

    // ---- transformer layers ----
    for (int i = 0; i < LLAY; ++i) {
        const size_t wOff = (size_t)i * DD * DD;
        hipLaunchKernelGGL(ln_rows, dim3(MTOK), dim3(256), 0, stream,
                           X, ln1_w + i * DD, ln1_b + i * DD, H);
        gemm(stream, H, wq + wOff, bq + i * DD, nullptr, Qb, MTOK, DD, DD, 0);
        gemm(stream, H, wk + wOff, bk + i * DD, nullptr, Kb, MTOK, DD, DD, 0);
        gemm(stream, H, wv + wOff, bv + i * DD, nullptr, Vb, MTOK, DD, DD, 0);
        hipLaunchKernelGGL(attn_scores, dim3(9, 9, BB * NHEAD), dim3(256), 0, stream, Qb, Kb, BIG);
        hipLaunchKernelGGL(softmax_rows, dim3(BB * NHEAD * SD / 4), dim3(256), 0, stream, BIG);
        hipLaunchKernelGGL(attn_av, dim3(9, BB * NHEAD), dim3(256), 0, stream, BIG, Vb, H);
        gemm(stream, H, wo + wOff, bo + i * DD, X, X, MTOK, DD, DD, 0);   // x += o@wo+bo
        hipLaunchKernelGGL(ln_rows, dim3(MTOK), dim3(256), 0, stream,
                           X, ln2_w + i * DD, ln2_b + i * DD, Qb);
        gemm(stream, Qb, w1 + (size_t)i * DD * DFFD, b1 + i * DFFD, nullptr, BIG,
             MTOK, DFFD, DD, 1);                                          // gelu(h@w1+b1)
        gemm(stream, BIG, w2 + (size_t)i * DFFD * DD, b2 + i * DD, X, X,
             MTOK, DD, DFFD, 0);                                          // x += .@w2+b2
    }

    // ---- final LN + PGSA + predictor + unpatchify ----
    hipLaunchKernelGGL(ln_rows, dim3(MTOK), dim3(256), 0, stream, X, normf_w, normf_b, H);
    hipLaunchKernelGGL(pgsa_k, dim3(BB * DD), dim3(256), 0, stream, H, RES);
    gemm(stream, RES, enpred_w, enpred_b, nullptr, BIG, MPAT, PDIM * PDIM * CCH, DD, 0);
    hipLaunchKernelGGL(unpatch_k, dim3(4096), dim3(256), 0, stream, BIG, out);
}

// Round 2
// 4935.751 us; speedup vs baseline: 2.1919x; 2.1919x over previous
//
#include <hip/hip_runtime.h>
#include <cstdint>
#include <cstddef>

// ---- problem dims ----
#define BB    8
#define CCH   2
#define IMGD  256
#define PDIM  16
#define DD    1024
#define LLAY  8
#define NHEAD 16
#define DFFD  4096
#define NTOK  256
#define SD    257
#define HDD   64
#define MTOK  (BB*SD)      // 2056
#define MPAT  (BB*NTOK)    // 2048
#define MPAD  2176         // 17*128 row padding for bf16 activation buffers

typedef unsigned short u16;
typedef __bf16 bf16x8 __attribute__((ext_vector_type(8)));
typedef float  f32x4  __attribute__((ext_vector_type(4)));

__device__ __forceinline__ u16 f2bf(float f) {
    uint32_t u = __float_as_uint(f);
    u += 0x7FFF + ((u >> 16) & 1);     // RNE
    return (u16)(u >> 16);
}

#define GLB(p)  ((const __attribute__((address_space(1))) void*)(uintptr_t)(p))
#define LDSP(p) ((__attribute__((address_space(3))) void*)(uint32_t)(uintptr_t)(p))

// =====================================================================
// bf16 MFMA GEMM, 128x128 tile, BK=32, 256 thr (4 waves 2x2, 64x64/wave).
// A [Mpad][K] bf16 row-major; BT [N][K] bf16 (i.e. B transposed).
// C[m,n] = act(sum_k A*B + bias[n]) (+ Cin[m,n]) -> fp32 or bf16.
// LDS: A 128x32 contiguous (8KB) + B 128x32 (8KB); global_load_lds width16.
// =====================================================================
template<int ACT, int OBF>
__global__ __launch_bounds__(256) void gemm128(
    const u16* __restrict__ A, const u16* __restrict__ BT,
    const float* __restrict__ bias, const float* __restrict__ Cin,
    void* __restrict__ Cout, int M, int N, int K)
{
    __shared__ u16 lds[8192];
    const int tid = threadIdx.x, wid = tid >> 6, lane = tid & 63;
    const int m0 = blockIdx.y * 128, n0 = blockIdx.x * 128;
    const int wm = (wid >> 1) * 64, wn = (wid & 1) * 64;
    const int srow = lane >> 2, scol = (lane & 3) * 8;
    const int l15 = lane & 15, loct = lane >> 4;

    f32x4 acc[4][4] = {};

    const size_t arow = (size_t)(m0 + wid * 16 + srow) * K + scol;
    const size_t brow = (size_t)(n0 + wid * 16 + srow) * K + scol;
    u16* ldsA = lds + wid * 512;          // wave chunk (1024B); +2048 for rows 64..127
    u16* ldsB = lds + 4096 + wid * 512;

    for (int k0 = 0; k0 < K; k0 += 32) {
        __builtin_amdgcn_global_load_lds(GLB(A  + arow + k0),                 LDSP(ldsA),        16, 0, 0);
        __builtin_amdgcn_global_load_lds(GLB(A  + arow + (size_t)64*K + k0),  LDSP(ldsA + 2048), 16, 0, 0);
        __builtin_amdgcn_global_load_lds(GLB(BT + brow + k0),                 LDSP(ldsB),        16, 0, 0);
        __builtin_amdgcn_global_load_lds(GLB(BT + brow + (size_t)64*K + k0),  LDSP(ldsB + 2048), 16, 0, 0);
        __syncthreads();
        bf16x8 af[4], bfr[4];
        #pragma unroll
        for (int i = 0; i < 4; ++i)
            af[i] = *(const bf16x8*)(lds + (wm + i * 16 + l15) * 32 + loct * 8);
        #pragma unroll
        for (int j = 0; j < 4; ++j)
            bfr[j] = *(const bf16x8*)(lds + 4096 + (wn + j * 16 + l15) * 32 + loct * 8);
        #pragma unroll
        for (int i = 0; i < 4; ++i)
            #pragma unroll
            for (int j = 0; j < 4; ++j)
                acc[i][j] = __builtin_amdgcn_mfma_f32_16x16x32_bf16(af[i], bfr[j], acc[i][j], 0, 0, 0);
        __syncthreads();
    }

    #pragma unroll
    for (int j = 0; j < 4; ++j) {
        const int col = n0 + wn + j * 16 + l15;
        const float bv = bias[col];
        #pragma unroll
        for (int i = 0; i < 4; ++i) {
            const int rbase = m0 + wm + i * 16 + loct * 4;
            #pragma unroll
            for (int r = 0; r < 4; ++r) {
                const int row = rbase + r;
                if (row < M) {
                    float v = acc[i][j][r] + bv;
                    if (ACT) v = 0.5f * v * (1.f + erff(v * 0.70710678118654752f));
                    if (Cin) v += Cin[(size_t)row * N + col];
                    if (OBF) ((u16*)Cout)[(size_t)row * N + col] = f2bf(v);
                    else     ((float*)Cout)[(size_t)row * N + col] = v;
                }
            }
        }
    }
}

// =====================================================================
// bf16 MFMA GEMM, 64x64 tile, BK=64 (two k-halves in LDS to keep 64B row
// stride), 256 thr (4 waves 2x2, 32x32/wave).
// =====================================================================
template<int ACT, int OBF>
__global__ __launch_bounds__(256) void gemm64(
    const u16* __restrict__ A, const u16* __restrict__ BT,
    const float* __restrict__ bias, const float* __restrict__ Cin,
    void* __restrict__ Cout, int M, int N, int K)
{
    __shared__ u16 lds[8192];   // A: [t][64][32] (2x2048), B: +4096 same
    const int tid = threadIdx.x, wid = tid >> 6, lane = tid & 63;
    const int m0 = blockIdx.y * 64, n0 = blockIdx.x * 64;
    const int wm = (wid >> 1) * 32, wn = (wid & 1) * 32;
    const int srow = lane >> 2, scol = (lane & 3) * 8;
    const int l15 = lane & 15, loct = lane >> 4;

    f32x4 acc[2][2] = {};

    const size_t arow = (size_t)(m0 + wid * 16 + srow) * K + scol;
    const size_t brow = (size_t)(n0 + wid * 16 + srow) * K + scol;
    u16* ldsA = lds + wid * 512;
    u16* ldsB = lds + 4096 + wid * 512;

    for (int k0 = 0; k0 < K; k0 += 64) {
        __builtin_amdgcn_global_load_lds(GLB(A  + arow + k0),      LDSP(ldsA),        16, 0, 0);
        __builtin_amdgcn_global_load_lds(GLB(A  + arow + k0 + 32), LDSP(ldsA + 2048), 16, 0, 0);
        __builtin_amdgcn_global_load_lds(GLB(BT + brow + k0),      LDSP(ldsB),        16, 0, 0);
        __builtin_amdgcn_global_load_lds(GLB(BT + brow + k0 + 32), LDSP(ldsB + 2048), 16, 0, 0);
        __syncthreads();
        #pragma unroll
        for (int t = 0; t < 2; ++t) {
            bf16x8 af[2], bfr[2];
            #pragma unroll
            for (int i = 0; i < 2; ++i)
                af[i] = *(const bf16x8*)(lds + t * 2048 + (wm + i * 16 + l15) * 32 + loct * 8);
            #pragma unroll
            for (int j = 0; j < 2; ++j)
                bfr[j] = *(const bf16x8*)(lds + 4096 + t * 2048 + (wn + j * 16 + l15) * 32 + loct * 8);
            #pragma unroll
            for (int i = 0; i < 2; ++i)
                #pragma unroll
                for (int j = 0; j < 2; ++j)
                    acc[i][j] = __builtin_amdgcn_mfma_f32_16x16x32_bf16(af[i], bfr[j], acc[i][j], 0, 0, 0);
        }
        __syncthreads();
    }

    #pragma unroll
    for (int j = 0; j < 2; ++j) {
        const int col = n0 + wn + j * 16 + l15;
        const float bv = bias[col];
        #pragma unroll
        for (int i = 0; i < 2; ++i) {
            const int rbase = m0 + wm + i * 16 + loct * 4;
            #pragma unroll
            for (int r = 0; r < 4; ++r) {
                const int row = rbase + r;
                if (row < M) {
                    float v = acc[i][j][r] + bv;
                    if (ACT) v = 0.5f * v * (1.f + erff(v * 0.70710678118654752f));
                    if (Cin) v += Cin[(size_t)row * N + col];
                    if (OBF) ((u16*)Cout)[(size_t)row * N + col] = f2bf(v);
                    else     ((float*)Cout)[(size_t)row * N + col] = v;
                }
            }
        }
    }
}

// =====================================================================
// Weight transpose+convert: W fp32 [K][N] -> WT bf16 [N][K]. 32x32 tiles.
// K,N multiples of 32 at all call sites.
// =====================================================================
__global__ __launch_bounds__(256) void transpose_bf16_k(
    const float* __restrict__ W, u16* __restrict__ WT, int K, int N)
{
    __shared__ float t[32][33];
    const int k0 = blockIdx.y * 32, n0 = blockIdx.x * 32;
    const int c = threadIdx.x & 31, rb = threadIdx.x >> 5;
    #pragma unroll
    for (int i = 0; i < 4; ++i) {
        const int r = rb + i * 8;
        t[r][c] = W[(size_t)(k0 + r) * N + n0 + c];
    }
    __syncthreads();
    #pragma unroll
    for (int i = 0; i < 4; ++i) {
        const int r = rb + i * 8;
        WT[(size_t)(n0 + r) * K + k0 + c] = f2bf(t[c][r]);
    }
}

// concat bq|bk|bv -> bias3072
__global__ __launch_bounds__(256) void cat3_k(const float* __restrict__ a,
                                              const float* __restrict__ b,
                                              const float* __restrict__ c,
                                              float* __restrict__ o)
{
    const int i = blockIdx.x * 256 + threadIdx.x;
    o[i] = (i < 1024) ? a[i] : (i < 2048 ? b[i - 1024] : c[i - 2048]);
}

// im2col (bf16 out): A[m=b*256+hp*16+wp][k=c*256+p*16+q]
__global__ __launch_bounds__(256) void im2col_k(const float* __restrict__ imgs,
                                                u16* __restrict__ Ao)
{
    const int idx = blockIdx.x * 256 + threadIdx.x;   // 2048*512
    const int k = idx & 511, m = idx >> 9;
    const int b = m >> 8, n = m & 255;
    const int hp = n >> 4, wp = n & 15;
    const int c = k >> 8, p = (k >> 4) & 15, q = k & 15;
    Ao[idx] = f2bf(imgs[(((size_t)b * CCH + c) * IMGD + hp * PDIM + p) * IMGD + wp * PDIM + q]);
}

__global__ __launch_bounds__(256) void build_x_k(const float* __restrict__ RES,
                                                 const float* __restrict__ cls,
                                                 float* __restrict__ X)
{
    const int idx = blockIdx.x * 256 + threadIdx.x;   // MTOK*DD
    const int d = idx & 1023;
    const int r = idx >> 10;
    const int b = r / SD;
    const int s = r - b * SD;
    X[idx] = (s == 0) ? cls[d] : RES[((size_t)(b * NTOK + s - 1)) * DD + d];
}

// LayerNorm over D=1024, one block per row. OBF: 0 -> fp32 out, 1 -> bf16 out.
template<int OBF>
__global__ __launch_bounds__(256) void ln_rows(const float* __restrict__ X,
                                               const float* __restrict__ w,
                                               const float* __restrict__ bsrc,
                                               void* __restrict__ Y)
{
    const int row = blockIdx.x;
    const int tid = threadIdx.x;
    const float* xr = X + (size_t)row * DD;
    const float4 v = *(const float4*)(xr + tid * 4);
    float s  = v.x + v.y + v.z + v.w;
    float s2 = v.x * v.x + v.y * v.y + v.z * v.z + v.w * v.w;
    #pragma unroll
    for (int off = 1; off < 64; off <<= 1) {
        s  += __shfl_xor(s, off);
        s2 += __shfl_xor(s2, off);
    }
    __shared__ float rs[4], rs2[4];
    if ((tid & 63) == 0) { rs[tid >> 6] = s; rs2[tid >> 6] = s2; }
    __syncthreads();
    s  = rs[0] + rs[1] + rs[2] + rs[3];
    s2 = rs2[0] + rs2[1] + rs2[2] + rs2[3];
    const float mu  = s * (1.f / 1024.f);
    const float var = fmaf(-mu, mu, s2 * (1.f / 1024.f));
    const float ri  = rsqrtf(var + 1e-5f);
    const float4 wv = *(const float4*)(w + tid * 4);
    const float4 bv = *(const float4*)(bsrc + tid * 4);
    float4 o;
    o.x = (v.x - mu) * ri * wv.x + bv.x;
    o.y = (v.y - mu) * ri * wv.y + bv.y;
    o.z = (v.z - mu) * ri * wv.z + bv.z;
    o.w = (v.w - mu) * ri * wv.w + bv.w;
    if (OBF) {
        ushort4 o4 = make_ushort4(f2bf(o.x), f2bf(o.y), f2bf(o.z), f2bf(o.w));
        *(ushort4*)((u16*)Y + (size_t)row * DD + tid * 4) = o4;
    } else {
        *(float4*)((float*)Y + (size_t)row * DD + tid * 4) = o;
    }
}

// =====================================================================
// Attention (fp32 vector this round). QKV fused buffer [M][3072]:
// q at +0, k at +1024, v at +2048 (within-row offset h*64+d).
// Logits stored fp16.
// =====================================================================
__global__ __launch_bounds__(256) void attn_scores(const float* __restrict__ QKV,
                                                   _Float16* __restrict__ Lg)
{
    const int bh = blockIdx.z;
    const int b = bh >> 4, h = bh & 15;
    const int q0 = blockIdx.x * 32, k0 = blockIdx.y * 32;
    __shared__ float Qs[32][65];
    __shared__ float KsT[64][33];
    const int tid = threadIdx.x;
    for (int li = tid; li < 2048; li += 256) {
        const int r = li >> 6, d = li & 63;
        const int sq = q0 + r, sk = k0 + r;
        Qs[r][d]  = (sq < SD) ? QKV[((size_t)(b * SD + sq)) * 3072 + h * HDD + d] : 0.f;
        KsT[d][r] = (sk < SD) ? QKV[((size_t)(b * SD + sk)) * 3072 + 1024 + h * HDD + d] : 0.f;
    }
    __syncthreads();
    const int tx = tid & 31, ty = tid >> 5;
    float acc[4] = {0.f, 0.f, 0.f, 0.f};
    for (int d = 0; d < 64; ++d) {
        const float kv = KsT[d][tx];
        #pragma unroll
        for (int i = 0; i < 4; ++i) acc[i] = fmaf(Qs[ty + 8 * i][d], kv, acc[i]);
    }
    const float dec = logf(1.f - exp2f(-1.f - (float)h));
    const int sk = k0 + tx;
    #pragma unroll
    for (int i = 0; i < 4; ++i) {
        const int sq = q0 + ty + 8 * i;
        if (sq < SD && sk < SD) {
            float mv = 0.f;
            if (sq > 0 && sk > 0) {
                const int nq = sq - 1, nk = sk - 1;
                const int dist = abs((nq >> 4) - (nk >> 4)) + abs((nq & 15) - (nk & 15));
                mv = dec * (float)dist;
            }
            Lg[((size_t)bh * SD + sq) * SD + sk] = (_Float16)(acc[i] * 0.125f + mv);
        }
    }
}

__global__ __launch_bounds__(256) void softmax_rows(_Float16* __restrict__ Lg)
{
    const int row = blockIdx.x * 4 + (threadIdx.x >> 6);
    const int lane = threadIdx.x & 63;
    _Float16* p = Lg + (size_t)row * SD;
    float v0 = (float)p[lane];
    float v1 = (float)p[lane + 64];
    float v2 = (float)p[lane + 128];
    float v3 = (float)p[lane + 192];
    float v4 = (lane == 0) ? (float)p[256] : -3.4e38f;
    float mx = fmaxf(fmaxf(fmaxf(v0, v1), fmaxf(v2, v3)), v4);
    #pragma unroll
    for (int off = 1; off < 64; off <<= 1) mx = fmaxf(mx, __shfl_xor(mx, off));
    const float e0 = expf(v0 - mx), e1 = expf(v1 - mx);
    const float e2 = expf(v2 - mx), e3 = expf(v3 - mx);
    const float e4 = (lane == 0) ? expf(v4 - mx) : 0.f;
    float sum = e0 + e1 + e2 + e3 + e4;
    #pragma unroll
    for (int off = 1; off < 64; off <<= 1) sum += __shfl_xor(sum, off);
    const float inv = 1.f / sum;
    p[lane]       = (_Float16)(e0 * inv);
    p[lane + 64]  = (_Float16)(e1 * inv);
    p[lane + 128] = (_Float16)(e2 * inv);
    p[lane + 192] = (_Float16)(e3 * inv);
    if (lane == 0) p[256] = (_Float16)(e4 * inv);
}

// O (bf16) [row][1024] at h*64+d  <-  P (fp16) x V (fp32, QKV+2048)
__global__ __launch_bounds__(256) void attn_av(const _Float16* __restrict__ Pm,
                                               const float* __restrict__ QKV,
                                               u16* __restrict__ O)
{
    const int bh = blockIdx.y;
    const int b = bh >> 4, h = bh & 15;
    const int q0 = blockIdx.x * 32;
    const int tid = threadIdx.x;
    const int d = tid & 63, qg = tid >> 6;
    __shared__ float Ps[32][33];
    __shared__ float Vs[32][64];
    float acc[8] = {};
    const _Float16* Prow = Pm + (size_t)bh * SD * SD;
    for (int k0 = 0; k0 < SD; k0 += 32) {
        for (int li = tid; li < 1024; li += 256) {
            const int q = li >> 5, kk = li & 31;
            const int sq = q0 + q, sk = k0 + kk;
            Ps[q][kk] = (sq < SD && sk < SD) ? (float)Prow[(size_t)sq * SD + sk] : 0.f;
        }
        for (int li = tid; li < 2048; li += 256) {
            const int kk = li >> 6, dd = li & 63;
            const int sk = k0 + kk;
            Vs[kk][dd] = (sk < SD) ? QKV[((size_t)(b * SD + sk)) * 3072 + 2048 + h * HDD + dd] : 0.f;
        }
        __syncthreads();
        #pragma unroll
        for (int kk = 0; kk < 32; ++kk) {
            const float vv = Vs[kk][d];
            #pragma unroll
            for (int i = 0; i < 8; ++i) acc[i] = fmaf(Ps[qg * 8 + i][kk], vv, acc[i]);
        }
        __syncthreads();
    }
    #pragma unroll
    for (int i = 0; i < 8; ++i) {
        const int sq = q0 + qg * 8 + i;
        if (sq < SD) O[((size_t)(b * SD + sq)) * DD + h * HDD + d] = f2bf(acc[i]);
    }
}

// PGSA gate + residual -> bf16 tokens
__global__ __launch_bounds__(256) void pgsa_k(const float* __restrict__ Xf,
                                              const float* __restrict__ RES,
                                              u16* __restrict__ TOK)
{
    const int bd = blockIdx.x;          // B*D
    const int b = bd >> 10, dch = bd & 1023;
    const int n = threadIdx.x;
    const float t = Xf[((size_t)(b * SD + 1 + n)) * DD + dch];
    __shared__ float red[4];
    float s = t;
    #pragma unroll
    for (int off = 1; off < 64; off <<= 1) s += __shfl_xor(s, off);
    if ((n & 63) == 0) red[n >> 6] = s;
    __syncthreads();
    const float mu = (red[0] + red[1] + red[2] + red[3]) * (1.f / 256.f);
    const float xm = t - mu;
    const float xm2 = xm * xm;
    __syncthreads();
    float s2 = xm2;
    #pragma unroll
    for (int off = 1; off < 64; off <<= 1) s2 += __shfl_xor(s2, off);
    if ((n & 63) == 0) red[n >> 6] = s2;
    __syncthreads();
    const float tot2 = red[0] + red[1] + red[2] + red[3];
    const float y = xm2 / (4.f * (tot2 * (1.f / 255.f) + 1e-4f)) + 0.5f;
    const float sig = 1.f / (1.f + expf(-y));
    const size_t ri = ((size_t)b * NTOK + n) * DD + dch;
    TOK[ri] = f2bf(fmaf(t, sig, RES[ri]));
}

__global__ __launch_bounds__(256) void unpatch_k(const float* __restrict__ PRED,
                                                 float* __restrict__ out)
{
    const int idx = blockIdx.x * 256 + threadIdx.x;   // 1,048,576
    const int j = idx & 255, i = (idx >> 8) & 255;
    const int c = (idx >> 16) & 1, b = idx >> 17;
    const int hp = i >> 4, p = i & 15, wp = j >> 4, q = j & 15;
    out[idx] = PRED[((size_t)b * NTOK + hp * 16 + wp) * 512 + (p * 16 + q) * 2 + c];
}

// =====================================================================
extern "C" void kernel_launch(void* const* d_in, const int* in_sizes, int n_in,
                              void* d_out, int out_size, void* d_ws, size_t ws_size,
                              hipStream_t stream)
{
    const float* imgs     = (const float*)d_in[0];
    const float* patch_w  = (const float*)d_in[1];
    const float* patch_b  = (const float*)d_in[2];
    const float* cls_tok  = (const float*)d_in[3];
    const float* ln1_w    = (const float*)d_in[4];
    const float* ln1_b    = (const float*)d_in[5];
    const float* wq       = (const float*)d_in[6];
    const float* wk       = (const float*)d_in[7];
    const float* wv       = (const float*)d_in[8];
    const float* bq       = (const float*)d_in[9];
    const float* bk       = (const float*)d_in[10];
    const float* bv       = (const float*)d_in[11];
    const float* wo       = (const float*)d_in[12];
    const float* bo       = (const float*)d_in[13];
    const float* ln2_w    = (const float*)d_in[14];
    const float* ln2_b    = (const float*)d_in[15];
    const float* w1       = (const float*)d_in[16];
    const float* b1       = (const float*)d_in[17];
    const float* w2       = (const float*)d_in[18];
    const float* b2       = (const float*)d_in[19];
    const float* normf_w  = (const float*)d_in[20];
    const float* normf_b  = (const float*)d_in[21];
    const float* enpred_w = (const float*)d_in[22];
    const float* enpred_b = (const float*)d_in[23];
    float* out = (float*)d_out;

    // ---- workspace layout (77.2 MB total; round-1 verified >= 84.3 MB) ----
    char* w = (char*)d_ws;
    float* X     = (float*)w;            w += (size_t)MTOK * DD * 4;      //  8.42 MB
    float* RES   = (float*)w;            w += (size_t)MPAT * DD * 4;      //  8.39 MB
    float* QKVb  = (float*)w;            w += (size_t)MTOK * 3072 * 4;    // 25.26 MB (also Hf at end)
    char*  UNION = w;                    w += (size_t)MPAD * DFFD * 2;    // 17.83 MB: im2col/LG(fp16)/GELUb/PRED
    u16*   Hb    = (u16*)w;              w += (size_t)MPAD * DD * 2;      //  4.46 MB (also TOKb)
    u16*   Ob    = (u16*)w;              w += (size_t)MPAD * DD * 2;      //  4.46 MB
    u16*   WT    = (u16*)w;              w += (size_t)DFFD * DD * 2;      //  8.39 MB
    float* bias3 = (float*)w;            w += 3072 * 4;

    u16*      IM2b  = (u16*)UNION;
    _Float16* LG    = (_Float16*)UNION;
    u16*      GELUb = (u16*)UNION;
    float*    PRED  = (float*)UNION;
    float*    Hf    = QKVb;
    u16*      TOKb  = Hb;

    // ---- patch embed ----
    hipLaunchKernelGGL(im2col_k, dim3(4096), dim3(256), 0, stream, imgs, IM2b);
    hipLaunchKernelGGL(transpose_bf16_k, dim3(DD / 32, 512 / 32), dim3(256), 0, stream,
                       patch_w, WT, 512, DD);                      // [512][1024] -> [1024][512]
    hipLaunchKernelGGL((gemm64<0,0>), dim3(DD / 64, MPAT / 64), dim3(256), 0, stream,
                       IM2b, WT, patch_b, (const float*)nullptr, (void*)RES, MPAT, DD, 512);
    hipLaunchKernelGGL(build_x_k, dim3(MTOK * DD / 256), dim3(256), 0, stream, RES, cls_tok, X);

    // ---- transformer layers ----
    for (int i = 0; i < LLAY; ++i) {
        const size_t wOff = (size_t)i * DD * DD;
        hipLaunchKernelGGL((ln_rows<1>), dim3(MTOK), dim3(256), 0, stream,
                           X, ln1_w + i * DD, ln1_b + i * DD, (void*)Hb);
        // QKV fused: WT[0..1023]=wq^T, [1024..2047]=wk^T, [2048..3071]=wv^T
        hipLaunchKernelGGL(transpose_bf16_k, dim3(32, 32), dim3(256), 0, stream,
                           wq + wOff, WT,                         DD, DD);
        hipLaunchKernelGGL(transpose_bf16_k, dim3(32, 32), dim3(256), 0, stream,
                           wk + wOff, WT + (size_t)1024 * DD,     DD, DD);
        hipLaunchKernelGGL(transpose_bf16_k, dim3(32, 32), dim3(256), 0, stream,
                           wv + wOff, WT + (size_t)2048 * DD,     DD, DD);
        hipLaunchKernelGGL(cat3_k, dim3(12), dim3(256), 0, stream,
                           bq + i * DD, bk + i * DD, bv + i * DD, bias3);
        hipLaunchKernelGGL((gemm128<0,0>), dim3(3072 / 128, 17), dim3(256), 0, stream,
                           Hb, WT, bias3, (const float*)nullptr, (void*)QKVb, MTOK, 3072, DD);
        hipLaunchKernelGGL(attn_scores, dim3(9, 9, BB * NHEAD), dim3(256), 0, stream, QKVb, LG);
        hipLaunchKernelGGL(softmax_rows, dim3(BB * NHEAD * SD / 4), dim3(256), 0, stream, LG);
        hipLaunchKernelGGL(attn_av, dim3(9, BB * NHEAD), dim3(256), 0, stream, LG, QKVb, Ob);
        hipLaunchKernelGGL(transpose_bf16_k, dim3(32, 32), dim3(256), 0, stream,
                           wo + wOff, WT, DD, DD);
        hipLaunchKernelGGL((gemm64<0,0>), dim3(DD / 64, 33), dim3(256), 0, stream,
                           Ob, WT, bo + i * DD, X, (void*)X, MTOK, DD, DD);
        hipLaunchKernelGGL((ln_rows<1>), dim3(MTOK), dim3(256), 0, stream,
                           X, ln2_w + i * DD, ln2_b + i * DD, (void*)Hb);
        hipLaunchKernelGGL(transpose_bf16_k, dim3(DFFD / 32, DD / 32), dim3(256), 0, stream,
                           w1 + (size_t)i * DD * DFFD, WT, DD, DFFD);   // -> [4096][1024]
        hipLaunchKernelGGL((gemm128<1,1>), dim3(DFFD / 128, 17), dim3(256), 0, stream,
                           Hb, WT, b1 + i * DFFD, (const float*)nullptr, (void*)GELUb, MTOK, DFFD, DD);
        hipLaunchKernelGGL(transpose_bf16_k, dim3(DD / 32, DFFD / 32), dim3(256), 0, stream,
                           w2 + (size_t)i * DFFD * DD, WT, DFFD, DD);   // -> [1024][4096]
        hipLaunchKernelGGL((gemm64<0,0>), dim3(DD / 64, 33), dim3(256), 0, stream,
                           GELUb, WT, b2 + i * DD, X, (void*)X, MTOK, DD, DFFD);
    }

    // ---- final LN + PGSA + predictor + unpatchify ----
    hipLaunchKernelGGL((ln_rows<0>), dim3(MTOK), dim3(256), 0, stream, X, normf_w, normf_b, (void*)Hf);
    hipLaunchKernelGGL(pgsa_k, dim3(BB * DD), dim3(256), 0, stream, Hf, RES, TOKb);
    hipLaunchKernelGGL(transpose_bf16_k, dim3(512 / 32, DD / 32), dim3(256), 0, stream,
                       enpred_w, WT, DD, 512);                    // [1024][512] -> [512][1024]
    hipLaunchKernelGGL((gemm64<0,0>), dim3(512 / 64, MPAT / 64), dim3(256), 0, stream,
                       TOKb, WT, enpred_b, (const float*)nullptr, (void*)PRED, MPAT, 512, DD);
    hipLaunchKernelGGL(unpatch_k, dim3(4096), dim3(256), 0, stream, PRED, out);
}

// Round 3
// 2147.197 us; speedup vs baseline: 5.0385x; 2.2987x over previous
//
#include <hip/hip_runtime.h>
#include <cstdint>
#include <cstddef>

// ---- problem dims ----
#define BB    8
#define CCH   2
#define IMGD  256
#define PDIM  16
#define DD    1024
#define LLAY  8
#define NHEAD 16
#define DFFD  4096
#define NTOK  256
#define SD    257
#define HDD   64
#define MTOK  (BB*SD)      // 2056
#define MPAT  (BB*NTOK)    // 2048
#define MPAD  2176         // 17*128 row padding for bf16 activation buffers
#define KPAD  288          // padded key count for VT (cols 257..287 zeroed)

typedef unsigned short u16;
typedef __bf16 bf16x8 __attribute__((ext_vector_type(8)));
typedef float  f32x4  __attribute__((ext_vector_type(4)));

__device__ __forceinline__ u16 f2bf(float f) {
    uint32_t u = __float_as_uint(f);
    u += 0x7FFF + ((u >> 16) & 1);     // RNE
    return (u16)(u >> 16);
}
__device__ __forceinline__ int imin(int a, int b) { return a < b ? a : b; }

#define GLB(p)  ((const __attribute__((address_space(1))) void*)(uintptr_t)(p))
#define LDSP(p) ((__attribute__((address_space(3))) void*)(uint32_t)(uintptr_t)(p))

// =====================================================================
// bf16 MFMA GEMM, 128x128 tile, BK=32, 256 thr (4 waves 2x2, 64x64/wave).
// A [Mpad][K] bf16 row-major; BT [N][K] bf16. ACT: GELU. OBF: bf16 out.
// =====================================================================
template<int ACT, int OBF>
__global__ __launch_bounds__(256) void gemm128(
    const u16* __restrict__ A, const u16* __restrict__ BT,
    const float* __restrict__ bias, const float* __restrict__ Cin,
    void* __restrict__ Cout, int M, int N, int K)
{
    __shared__ u16 lds[8192];
    const int tid = threadIdx.x, wid = tid >> 6, lane = tid & 63;
    const int m0 = blockIdx.y * 128, n0 = blockIdx.x * 128;
    const int wm = (wid >> 1) * 64, wn = (wid & 1) * 64;
    const int srow = lane >> 2, scol = (lane & 3) * 8;
    const int l15 = lane & 15, loct = lane >> 4;

    f32x4 acc[4][4] = {};

    const size_t arow = (size_t)(m0 + wid * 16 + srow) * K + scol;
    const size_t brow = (size_t)(n0 + wid * 16 + srow) * K + scol;
    u16* ldsA = lds + wid * 512;
    u16* ldsB = lds + 4096 + wid * 512;

    for (int k0 = 0; k0 < K; k0 += 32) {
        __builtin_amdgcn_global_load_lds(GLB(A  + arow + k0),                 LDSP(ldsA),        16, 0, 0);
        __builtin_amdgcn_global_load_lds(GLB(A  + arow + (size_t)64*K + k0),  LDSP(ldsA + 2048), 16, 0, 0);
        __builtin_amdgcn_global_load_lds(GLB(BT + brow + k0),                 LDSP(ldsB),        16, 0, 0);
        __builtin_amdgcn_global_load_lds(GLB(BT + brow + (size_t)64*K + k0),  LDSP(ldsB + 2048), 16, 0, 0);
        __syncthreads();
        bf16x8 af[4], bfr[4];
        #pragma unroll
        for (int i = 0; i < 4; ++i)
            af[i] = *(const bf16x8*)(lds + (wm + i * 16 + l15) * 32 + loct * 8);
        #pragma unroll
        for (int j = 0; j < 4; ++j)
            bfr[j] = *(const bf16x8*)(lds + 4096 + (wn + j * 16 + l15) * 32 + loct * 8);
        #pragma unroll
        for (int i = 0; i < 4; ++i)
            #pragma unroll
            for (int j = 0; j < 4; ++j)
                acc[i][j] = __builtin_amdgcn_mfma_f32_16x16x32_bf16(af[i], bfr[j], acc[i][j], 0, 0, 0);
        __syncthreads();
    }

    #pragma unroll
    for (int j = 0; j < 4; ++j) {
        const int col = n0 + wn + j * 16 + l15;
        const float bv = bias[col];
        #pragma unroll
        for (int i = 0; i < 4; ++i) {
            const int rbase = m0 + wm + i * 16 + loct * 4;
            #pragma unroll
            for (int r = 0; r < 4; ++r) {
                const int row = rbase + r;
                if (row < M) {
                    float v = acc[i][j][r] + bv;
                    if (ACT) v = 0.5f * v * (1.f + erff(v * 0.70710678118654752f));
                    if (Cin) v += Cin[(size_t)row * N + col];
                    if (OBF) ((u16*)Cout)[(size_t)row * N + col] = f2bf(v);
                    else     ((float*)Cout)[(size_t)row * N + col] = v;
                }
            }
        }
    }
}

// =====================================================================
// QKV GEMM: same mainloop, N=3072. Epilogue splits:
//   cols 0..2047   -> QKb [row][2048]        (q | k), bf16
//   cols 2048..3071-> VTg [(b*1024+hd)][KPAD] at col=key (V transposed), bf16
// =====================================================================
__global__ __launch_bounds__(256) void gemm_qkv(
    const u16* __restrict__ A, const u16* __restrict__ BT,
    const float* __restrict__ bias,
    u16* __restrict__ QKb, u16* __restrict__ VTg, int M, int K)
{
    __shared__ u16 lds[8192];
    const int tid = threadIdx.x, wid = tid >> 6, lane = tid & 63;
    const int m0 = blockIdx.y * 128, n0 = blockIdx.x * 128;
    const int wm = (wid >> 1) * 64, wn = (wid & 1) * 64;
    const int srow = lane >> 2, scol = (lane & 3) * 8;
    const int l15 = lane & 15, loct = lane >> 4;

    f32x4 acc[4][4] = {};
    const size_t arow = (size_t)(m0 + wid * 16 + srow) * K + scol;
    const size_t brow = (size_t)(n0 + wid * 16 + srow) * K + scol;
    u16* ldsA = lds + wid * 512;
    u16* ldsB = lds + 4096 + wid * 512;

    for (int k0 = 0; k0 < K; k0 += 32) {
        __builtin_amdgcn_global_load_lds(GLB(A  + arow + k0),                 LDSP(ldsA),        16, 0, 0);
        __builtin_amdgcn_global_load_lds(GLB(A  + arow + (size_t)64*K + k0),  LDSP(ldsA + 2048), 16, 0, 0);
        __builtin_amdgcn_global_load_lds(GLB(BT + brow + k0),                 LDSP(ldsB),        16, 0, 0);
        __builtin_amdgcn_global_load_lds(GLB(BT + brow + (size_t)64*K + k0),  LDSP(ldsB + 2048), 16, 0, 0);
        __syncthreads();
        bf16x8 af[4], bfr[4];
        #pragma unroll
        for (int i = 0; i < 4; ++i)
            af[i] = *(const bf16x8*)(lds + (wm + i * 16 + l15) * 32 + loct * 8);
        #pragma unroll
        for (int j = 0; j < 4; ++j)
            bfr[j] = *(const bf16x8*)(lds + 4096 + (wn + j * 16 + l15) * 32 + loct * 8);
        #pragma unroll
        for (int i = 0; i < 4; ++i)
            #pragma unroll
            for (int j = 0; j < 4; ++j)
                acc[i][j] = __builtin_amdgcn_mfma_f32_16x16x32_bf16(af[i], bfr[j], acc[i][j], 0, 0, 0);
        __syncthreads();
    }

    #pragma unroll
    for (int j = 0; j < 4; ++j) {
        const int col = n0 + wn + j * 16 + l15;
        const float bv = bias[col];
        #pragma unroll
        for (int i = 0; i < 4; ++i) {
            const int rbase = m0 + wm + i * 16 + loct * 4;
            #pragma unroll
            for (int r = 0; r < 4; ++r) {
                const int row = rbase + r;
                if (row < M) {
                    const float v = acc[i][j][r] + bv;
                    if (col < 2048) {
                        QKb[(size_t)row * 2048 + col] = f2bf(v);
                    } else {
                        const int b = row / SD;
                        const int key = row - b * SD;
                        VTg[((size_t)b * 1024 + (col - 2048)) * KPAD + key] = f2bf(v);
                    }
                }
            }
        }
    }
}

// =====================================================================
// bf16 MFMA GEMM, 64x64 tile, BK=64, 256 thr (4 waves 2x2, 32x32/wave).
// =====================================================================
template<int ACT, int OBF>
__global__ __launch_bounds__(256) void gemm64(
    const u16* __restrict__ A, const u16* __restrict__ BT,
    const float* __restrict__ bias, const float* __restrict__ Cin,
    void* __restrict__ Cout, int M, int N, int K)
{
    __shared__ u16 lds[8192];
    const int tid = threadIdx.x, wid = tid >> 6, lane = tid & 63;
    const int m0 = blockIdx.y * 64, n0 = blockIdx.x * 64;
    const int wm = (wid >> 1) * 32, wn = (wid & 1) * 32;
    const int srow = lane >> 2, scol = (lane & 3) * 8;
    const int l15 = lane & 15, loct = lane >> 4;

    f32x4 acc[2][2] = {};
    const size_t arow = (size_t)(m0 + wid * 16 + srow) * K + scol;
    const size_t brow = (size_t)(n0 + wid * 16 + srow) * K + scol;
    u16* ldsA = lds + wid * 512;
    u16* ldsB = lds + 4096 + wid * 512;

    for (int k0 = 0; k0 < K; k0 += 64) {
        __builtin_amdgcn_global_load_lds(GLB(A  + arow + k0),      LDSP(ldsA),        16, 0, 0);
        __builtin_amdgcn_global_load_lds(GLB(A  + arow + k0 + 32), LDSP(ldsA + 2048), 16, 0, 0);
        __builtin_amdgcn_global_load_lds(GLB(BT + brow + k0),      LDSP(ldsB),        16, 0, 0);
        __builtin_amdgcn_global_load_lds(GLB(BT + brow + k0 + 32), LDSP(ldsB + 2048), 16, 0, 0);
        __syncthreads();
        #pragma unroll
        for (int t = 0; t < 2; ++t) {
            bf16x8 af[2], bfr[2];
            #pragma unroll
            for (int i = 0; i < 2; ++i)
                af[i] = *(const bf16x8*)(lds + t * 2048 + (wm + i * 16 + l15) * 32 + loct * 8);
            #pragma unroll
            for (int j = 0; j < 2; ++j)
                bfr[j] = *(const bf16x8*)(lds + 4096 + t * 2048 + (wn + j * 16 + l15) * 32 + loct * 8);
            #pragma unroll
            for (int i = 0; i < 2; ++i)
                #pragma unroll
                for (int j = 0; j < 2; ++j)
                    acc[i][j] = __builtin_amdgcn_mfma_f32_16x16x32_bf16(af[i], bfr[j], acc[i][j], 0, 0, 0);
        }
        __syncthreads();
    }

    #pragma unroll
    for (int j = 0; j < 2; ++j) {
        const int col = n0 + wn + j * 16 + l15;
        const float bv = bias[col];
        #pragma unroll
        for (int i = 0; i < 2; ++i) {
            const int rbase = m0 + wm + i * 16 + loct * 4;
            #pragma unroll
            for (int r = 0; r < 4; ++r) {
                const int row = rbase + r;
                if (row < M) {
                    float v = acc[i][j][r] + bv;
                    if (ACT) v = 0.5f * v * (1.f + erff(v * 0.70710678118654752f));
                    if (Cin) v += Cin[(size_t)row * N + col];
                    if (OBF) ((u16*)Cout)[(size_t)row * N + col] = f2bf(v);
                    else     ((float*)Cout)[(size_t)row * N + col] = v;
                }
            }
        }
    }
}

// =====================================================================
// Fused attention, one (b,h) per blockIdx.x, 64 q-rows per block (wave=16).
// QKb bf16 [2056][2048] (q|k per head at h*64), VTg bf16 [b*1024+hd][KPAD]
// (keys 257..KPAD-1 are zero). Output O bf16 [row][1024].
// S=QK^T via MFMA (frags straight from global); softmax in regs (16-lane
// shfl); P through per-wave LDS (C-layout -> A-layout); O=PV via MFMA.
// No __syncthreads anywhere.
// =====================================================================
__global__ __launch_bounds__(256) void attn_fused(
    const u16* __restrict__ QKb, const u16* __restrict__ VTg,
    u16* __restrict__ O)
{
    __shared__ u16 P[4][16][296];          // 37.9 KB
    const int tid = threadIdx.x, wid = tid >> 6, lane = tid & 63;
    const int l15 = lane & 15, loct = lane >> 4;
    const int bh = blockIdx.x, b = bh >> 4, h = bh & 15;
    const int q0 = blockIdx.y * 64 + wid * 16;

    const size_t qkbase = (size_t)b * SD * 2048 + h * 64;
    const u16* qp = QKb + qkbase + (size_t)imin(q0 + l15, SD - 1) * 2048;
    const bf16x8 qf0 = *(const bf16x8*)(qp + loct * 8);
    const bf16x8 qf1 = *(const bf16x8*)(qp + 32 + loct * 8);

    f32x4 s[17];
    #pragma unroll
    for (int nt = 0; nt < 17; ++nt) {
        const u16* kp = QKb + qkbase + (size_t)imin(nt * 16 + l15, SD - 1) * 2048 + 1024;
        const bf16x8 kf0 = *(const bf16x8*)(kp + loct * 8);
        const bf16x8 kf1 = *(const bf16x8*)(kp + 32 + loct * 8);
        f32x4 a = {};
        a = __builtin_amdgcn_mfma_f32_16x16x32_bf16(qf0, kf0, a, 0, 0, 0);
        a = __builtin_amdgcn_mfma_f32_16x16x32_bf16(qf1, kf1, a, 0, 0, 0);
        s[nt] = a;
    }

    // ---- mask + softmax (C-layout: col=l15 -> key, row=loct*4+r -> q) ----
    const float dec = logf(1.f - exp2f(-1.f - (float)h));
    const int qb = q0 + loct * 4;
    float rmax[4] = {-3.4e38f, -3.4e38f, -3.4e38f, -3.4e38f};
    #pragma unroll
    for (int nt = 0; nt < 17; ++nt) {
        const int key = nt * 16 + l15;
        #pragma unroll
        for (int r = 0; r < 4; ++r) {
            float v;
            if (key >= SD) {
                v = -1e30f;
            } else {
                v = s[nt][r] * 0.125f;
                const int q = qb + r;
                if (q > 0 && key > 0) {
                    const int nq = q - 1, nk = key - 1;
                    const int dist = abs((nq >> 4) - (nk >> 4)) + abs((nq & 15) - (nk & 15));
                    v += dec * (float)dist;
                }
            }
            s[nt][r] = v;
            rmax[r] = fmaxf(rmax[r], v);
        }
    }
    #pragma unroll
    for (int r = 0; r < 4; ++r) {
        #pragma unroll
        for (int m = 1; m < 16; m <<= 1) rmax[r] = fmaxf(rmax[r], __shfl_xor(rmax[r], m));
    }
    float rsum[4] = {0.f, 0.f, 0.f, 0.f};
    #pragma unroll
    for (int nt = 0; nt < 17; ++nt)
        #pragma unroll
        for (int r = 0; r < 4; ++r) {
            const float e = __expf(s[nt][r] - rmax[r]);
            s[nt][r] = e;
            rsum[r] += e;
        }
    #pragma unroll
    for (int r = 0; r < 4; ++r) {
        #pragma unroll
        for (int m = 1; m < 16; m <<= 1) rsum[r] += __shfl_xor(rsum[r], m);
        rsum[r] = 1.f / rsum[r];
    }
    #pragma unroll
    for (int nt = 0; nt < 17; ++nt)
        #pragma unroll
        for (int r = 0; r < 4; ++r)
            P[wid][loct * 4 + r][nt * 16 + l15] = f2bf(s[nt][r] * rsum[r]);
    // zero P pad cols 272..287 (per wave: 16 rows x 16 cols = 64 lanes x 4)
    {
        const int rr = lane >> 2, cc = (lane & 3) * 4;
        #pragma unroll
        for (int i = 0; i < 4; ++i) P[wid][rr][272 + cc + i] = 0;
    }

    // ---- O = P @ V ----
    f32x4 o[4] = {};
    const u16* vrow = VTg + ((size_t)b * 1024 + h * 64) * KPAD;
    #pragma unroll
    for (int ks = 0; ks < 9; ++ks) {
        const bf16x8 pf = *(const bf16x8*)&P[wid][l15][ks * 32 + loct * 8];
        #pragma unroll
        for (int j = 0; j < 4; ++j) {
            const bf16x8 vf = *(const bf16x8*)(vrow + (size_t)(j * 16 + l15) * KPAD + ks * 32 + loct * 8);
            o[j] = __builtin_amdgcn_mfma_f32_16x16x32_bf16(pf, vf, o[j], 0, 0, 0);
        }
    }
    #pragma unroll
    for (int j = 0; j < 4; ++j)
        #pragma unroll
        for (int r = 0; r < 4; ++r) {
            const int q = qb + r;
            if (q < SD) O[((size_t)(b * SD + q)) * DD + h * 64 + j * 16 + l15] = f2bf(o[j][r]);
        }
}

// =====================================================================
// Weight transpose+convert: W fp32 [K][N] -> WT bf16 [N][K]. 32x32 tiles.
// =====================================================================
__global__ __launch_bounds__(256) void transpose_bf16_k(
    const float* __restrict__ W, u16* __restrict__ WT, int K, int N)
{
    __shared__ float t[32][33];
    const int k0 = blockIdx.y * 32, n0 = blockIdx.x * 32;
    const int c = threadIdx.x & 31, rb = threadIdx.x >> 5;
    #pragma unroll
    for (int i = 0; i < 4; ++i) {
        const int r = rb + i * 8;
        t[r][c] = W[(size_t)(k0 + r) * N + n0 + c];
    }
    __syncthreads();
    #pragma unroll
    for (int i = 0; i < 4; ++i) {
        const int r = rb + i * 8;
        WT[(size_t)(n0 + r) * K + k0 + c] = f2bf(t[c][r]);
    }
}

__global__ __launch_bounds__(256) void cat3_k(const float* __restrict__ a,
                                              const float* __restrict__ b,
                                              const float* __restrict__ c,
                                              float* __restrict__ o)
{
    const int i = blockIdx.x * 256 + threadIdx.x;
    o[i] = (i < 1024) ? a[i] : (i < 2048 ? b[i - 1024] : c[i - 2048]);
}

__global__ __launch_bounds__(256) void im2col_k(const float* __restrict__ imgs,
                                                u16* __restrict__ Ao)
{
    const int idx = blockIdx.x * 256 + threadIdx.x;
    const int k = idx & 511, m = idx >> 9;
    const int b = m >> 8, n = m & 255;
    const int hp = n >> 4, wp = n & 15;
    const int c = k >> 8, p = (k >> 4) & 15, q = k & 15;
    Ao[idx] = f2bf(imgs[(((size_t)b * CCH + c) * IMGD + hp * PDIM + p) * IMGD + wp * PDIM + q]);
}

__global__ __launch_bounds__(256) void build_x_k(const float* __restrict__ RES,
                                                 const float* __restrict__ cls,
                                                 float* __restrict__ X)
{
    const int idx = blockIdx.x * 256 + threadIdx.x;
    const int d = idx & 1023;
    const int r = idx >> 10;
    const int b = r / SD;
    const int s = r - b * SD;
    X[idx] = (s == 0) ? cls[d] : RES[((size_t)(b * NTOK + s - 1)) * DD + d];
}

template<int OBF>
__global__ __launch_bounds__(256) void ln_rows(const float* __restrict__ X,
                                               const float* __restrict__ w,
                                               const float* __restrict__ bsrc,
                                               void* __restrict__ Y)
{
    const int row = blockIdx.x;
    const int tid = threadIdx.x;
    const float* xr = X + (size_t)row * DD;
    const float4 v = *(const float4*)(xr + tid * 4);
    float s  = v.x + v.y + v.z + v.w;
    float s2 = v.x * v.x + v.y * v.y + v.z * v.z + v.w * v.w;
    #pragma unroll
    for (int off = 1; off < 64; off <<= 1) {
        s  += __shfl_xor(s, off);
        s2 += __shfl_xor(s2, off);
    }
    __shared__ float rs[4], rs2[4];
    if ((tid & 63) == 0) { rs[tid >> 6] = s; rs2[tid >> 6] = s2; }
    __syncthreads();
    s  = rs[0] + rs[1] + rs[2] + rs[3];
    s2 = rs2[0] + rs2[1] + rs2[2] + rs2[3];
    const float mu  = s * (1.f / 1024.f);
    const float var = fmaf(-mu, mu, s2 * (1.f / 1024.f));
    const float ri  = rsqrtf(var + 1e-5f);
    const float4 wv = *(const float4*)(w + tid * 4);
    const float4 bv = *(const float4*)(bsrc + tid * 4);
    float4 o;
    o.x = (v.x - mu) * ri * wv.x + bv.x;
    o.y = (v.y - mu) * ri * wv.y + bv.y;
    o.z = (v.z - mu) * ri * wv.z + bv.z;
    o.w = (v.w - mu) * ri * wv.w + bv.w;
    if (OBF) {
        ushort4 o4 = make_ushort4(f2bf(o.x), f2bf(o.y), f2bf(o.z), f2bf(o.w));
        *(ushort4*)((u16*)Y + (size_t)row * DD + tid * 4) = o4;
    } else {
        *(float4*)((float*)Y + (size_t)row * DD + tid * 4) = o;
    }
}

__global__ __launch_bounds__(256) void pgsa_k(const float* __restrict__ Xf,
                                              const float* __restrict__ RES,
                                              u16* __restrict__ TOK)
{
    const int bd = blockIdx.x;
    const int b = bd >> 10, dch = bd & 1023;
    const int n = threadIdx.x;
    const float t = Xf[((size_t)(b * SD + 1 + n)) * DD + dch];
    __shared__ float red[4];
    float s = t;
    #pragma unroll
    for (int off = 1; off < 64; off <<= 1) s += __shfl_xor(s, off);
    if ((n & 63) == 0) red[n >> 6] = s;
    __syncthreads();
    const float mu = (red[0] + red[1] + red[2] + red[3]) * (1.f / 256.f);
    const float xm = t - mu;
    const float xm2 = xm * xm;
    __syncthreads();
    float s2 = xm2;
    #pragma unroll
    for (int off = 1; off < 64; off <<= 1) s2 += __shfl_xor(s2, off);
    if ((n & 63) == 0) red[n >> 6] = s2;
    __syncthreads();
    const float tot2 = red[0] + red[1] + red[2] + red[3];
    const float y = xm2 / (4.f * (tot2 * (1.f / 255.f) + 1e-4f)) + 0.5f;
    const float sig = 1.f / (1.f + expf(-y));
    const size_t ri = ((size_t)b * NTOK + n) * DD + dch;
    TOK[ri] = f2bf(fmaf(t, sig, RES[ri]));
}

__global__ __launch_bounds__(256) void unpatch_k(const float* __restrict__ PRED,
                                                 float* __restrict__ out)
{
    const int idx = blockIdx.x * 256 + threadIdx.x;
    const int j = idx & 255, i = (idx >> 8) & 255;
    const int c = (idx >> 16) & 1, b = idx >> 17;
    const int hp = i >> 4, p = i & 15, wp = j >> 4, q = j & 15;
    out[idx] = PRED[((size_t)b * NTOK + hp * 16 + wp) * 512 + (p * 16 + q) * 2 + c];
}

// =====================================================================
extern "C" void kernel_launch(void* const* d_in, const int* in_sizes, int n_in,
                              void* d_out, int out_size, void* d_ws, size_t ws_size,
                              hipStream_t stream)
{
    const float* imgs     = (const float*)d_in[0];
    const float* patch_w  = (const float*)d_in[1];
    const float* patch_b  = (const float*)d_in[2];
    const float* cls_tok  = (const float*)d_in[3];
    const float* ln1_w    = (const float*)d_in[4];
    const float* ln1_b    = (const float*)d_in[5];
    const float* wq       = (const float*)d_in[6];
    const float* wk       = (const float*)d_in[7];
    const float* wv       = (const float*)d_in[8];
    const float* bq       = (const float*)d_in[9];
    const float* bk       = (const float*)d_in[10];
    const float* bv       = (const float*)d_in[11];
    const float* wo       = (const float*)d_in[12];
    const float* bo       = (const float*)d_in[13];
    const float* ln2_w    = (const float*)d_in[14];
    const float* ln2_b    = (const float*)d_in[15];
    const float* w1       = (const float*)d_in[16];
    const float* b1       = (const float*)d_in[17];
    const float* w2       = (const float*)d_in[18];
    const float* b2       = (const float*)d_in[19];
    const float* normf_w  = (const float*)d_in[20];
    const float* normf_b  = (const float*)d_in[21];
    const float* enpred_w = (const float*)d_in[22];
    const float* enpred_b = (const float*)d_in[23];
    float* out = (float*)d_out;

    // ---- workspace layout (~65.6 MB; round-2 verified >= 77.2 MB) ----
    char* w = (char*)d_ws;
    float* X     = (float*)w;            w += (size_t)MTOK * DD * 4;        //  8.42 MB
    float* RES   = (float*)w;            w += (size_t)MPAT * DD * 4;        //  8.39 MB
    u16*   QKb   = (u16*)w;              w += (size_t)MPAD * 2048 * 2;      //  8.91 MB (alias Hf fp32 8.42)
    u16*   VTg   = (u16*)w;              w += (size_t)BB * 1024 * KPAD * 2; //  4.72 MB
    char*  UNION = w;                    w += (size_t)MPAD * DFFD * 2;      // 17.83 MB: im2col/GELUb/PRED
    u16*   Hb    = (u16*)w;              w += (size_t)MPAD * DD * 2;        //  4.46 MB (alias TOKb)
    u16*   Ob    = (u16*)w;              w += (size_t)MPAD * DD * 2;        //  4.46 MB
    u16*   WT    = (u16*)w;              w += (size_t)DFFD * DD * 2;        //  8.39 MB
    float* bias3 = (float*)w;            w += 3072 * 4;

    u16*   IM2b  = (u16*)UNION;
    u16*   GELUb = (u16*)UNION;
    float* PRED  = (float*)UNION;
    float* Hf    = (float*)QKb;
    u16*   TOKb  = Hb;

    // zero VT pad cols (gemm_qkv writes only keys 0..256; pad must be 0)
    hipMemsetAsync(VTg, 0, (size_t)BB * 1024 * KPAD * 2, stream);

    // ---- patch embed ----
    hipLaunchKernelGGL(im2col_k, dim3(4096), dim3(256), 0, stream, imgs, IM2b);
    hipLaunchKernelGGL(transpose_bf16_k, dim3(DD / 32, 512 / 32), dim3(256), 0, stream,
                       patch_w, WT, 512, DD);
    hipLaunchKernelGGL((gemm64<0,0>), dim3(DD / 64, MPAT / 64), dim3(256), 0, stream,
                       IM2b, WT, patch_b, (const float*)nullptr, (void*)RES, MPAT, DD, 512);
    hipLaunchKernelGGL(build_x_k, dim3(MTOK * DD / 256), dim3(256), 0, stream, RES, cls_tok, X);

    // ---- transformer layers ----
    for (int i = 0; i < LLAY; ++i) {
        const size_t wOff = (size_t)i * DD * DD;
        hipLaunchKernelGGL((ln_rows<1>), dim3(MTOK), dim3(256), 0, stream,
                           X, ln1_w + i * DD, ln1_b + i * DD, (void*)Hb);
        hipLaunchKernelGGL(transpose_bf16_k, dim3(32, 32), dim3(256), 0, stream,
                           wq + wOff, WT,                     DD, DD);
        hipLaunchKernelGGL(transpose_bf16_k, dim3(32, 32), dim3(256), 0, stream,
                           wk + wOff, WT + (size_t)1024 * DD, DD, DD);
        hipLaunchKernelGGL(transpose_bf16_k, dim3(32, 32), dim3(256), 0, stream,
                           wv + wOff, WT + (size_t)2048 * DD, DD, DD);
        hipLaunchKernelGGL(cat3_k, dim3(12), dim3(256), 0, stream,
                           bq + i * DD, bk + i * DD, bv + i * DD, bias3);
        hipLaunchKernelGGL(gemm_qkv, dim3(3072 / 128, 17), dim3(256), 0, stream,
                           Hb, WT, bias3, QKb, VTg, MTOK, DD);
        hipLaunchKernelGGL(attn_fused, dim3(BB * NHEAD, 5), dim3(256), 0, stream,
                           QKb, VTg, Ob);
        hipLaunchKernelGGL(transpose_bf16_k, dim3(32, 32), dim3(256), 0, stream,
                           wo + wOff, WT, DD, DD);
        hipLaunchKernelGGL((gemm64<0,0>), dim3(DD / 64, 33), dim3(256), 0, stream,
                           Ob, WT, bo + i * DD, X, (void*)X, MTOK, DD, DD);
        hipLaunchKernelGGL((ln_rows<1>), dim3(MTOK), dim3(256), 0, stream,
                           X, ln2_w + i * DD, ln2_b + i * DD, (void*)Hb);
        hipLaunchKernelGGL(transpose_bf16_k, dim3(DFFD / 32, DD / 32), dim3(256), 0, stream,
                           w1 + (size_t)i * DD * DFFD, WT, DD, DFFD);
        hipLaunchKernelGGL((gemm128<1,1>), dim3(DFFD / 128, 17), dim3(256), 0, stream,
                           Hb, WT, b1 + i * DFFD, (const float*)nullptr, (void*)GELUb, MTOK, DFFD, DD);
        hipLaunchKernelGGL(transpose_bf16_k, dim3(DD / 32, DFFD / 32), dim3(256), 0, stream,
                           w2 + (size_t)i * DFFD * DD, WT, DFFD, DD);
        hipLaunchKernelGGL((gemm64<0,0>), dim3(DD / 64, 33), dim3(256), 0, stream,
                           GELUb, WT, b2 + i * DD, X, (void*)X, MTOK, DD, DFFD);
    }

    // ---- final LN + PGSA + predictor + unpatchify ----
    hipLaunchKernelGGL((ln_rows<0>), dim3(MTOK), dim3(256), 0, stream, X, normf_w, normf_b, (void*)Hf);
    hipLaunchKernelGGL(pgsa_k, dim3(BB * DD), dim3(256), 0, stream, Hf, RES, TOKb);
    hipLaunchKernelGGL(transpose_bf16_k, dim3(512 / 32, DD / 32), dim3(256), 0, stream,
                       enpred_w, WT, DD, 512);
    hipLaunchKernelGGL((gemm64<0,0>), dim3(512 / 64, MPAT / 64), dim3(256), 0, stream,
                       TOKb, WT, enpred_b, (const float*)nullptr, (void*)PRED, MPAT, 512, DD);
    hipLaunchKernelGGL(unpatch_k, dim3(4096), dim3(256), 0, stream, PRED, out);
}